// Round 12
// baseline (1032.700 us; speedup 1.0000x reference)
//
#include <hip/hip_runtime.h>

// GCN-EEGNet forward, MI355X. Dtype-adaptive (fp32/bf16 detected in K0 via
// adjacency sentinel). Weights in ws, wave-uniform -> SGPR. Intermediates
// f16. Round-12: r11 o-split REVERTED (it doubled VMEM issue count: each
// window loaded by both osel waves -> +25us/launch; occupancy 58% didn't
// help -> k3 is issue/VALU-bound, not occupancy-starved). Keep r11 k1
// vectorized staging + k2 8-c split. k3 = r10 form: 8 t/thread, 8 o/thread,
// dot2, each window loaded once (16.8M loads). 16B dwordx4 everywhere.
// Pipeline: K0 -> K1 conv1+bn -> 3x [K2 graph einsum -> K3 gconv+bn+elu] ->
// K4 dw+bn+elu+pool4 -> K5 sep+bn+elu -> K6 pool8+fc.

#define B_   32
#define C_   64
#define T_   4000
#define F1_  8
#define TP_  1000
#define W2_  1001
#define MAXDEG 16

typedef _Float16 h16x2 __attribute__((ext_vector_type(2)));

static __device__ __forceinline__ float bf2f(unsigned short h) {
  union { unsigned int u; float f; } v; v.u = ((unsigned int)h) << 16; return v.f;
}
static __device__ __forceinline__ unsigned short f2bf(float f) {
  union { float f; unsigned int u; } v; v.f = f;
  unsigned int r = v.u + 0x7FFFu + ((v.u >> 16) & 1u);
  return (unsigned short)(r >> 16);
}
static __device__ __forceinline__ float lo_h(unsigned int u) {
  union { unsigned int u; _Float16 h[2]; } v; v.u = u; return (float)v.h[0];
}
static __device__ __forceinline__ float hi_h(unsigned int u) {
  union { unsigned int u; _Float16 h[2]; } v; v.u = u; return (float)v.h[1];
}
static __device__ __forceinline__ unsigned int pack2h(float a, float b) {
  union { _Float16 h[2]; unsigned int u; } v;
  v.h[0] = (_Float16)a; v.h[1] = (_Float16)b; return v.u;
}
static __device__ __forceinline__ h16x2 as_h2(unsigned int u) {
  union { unsigned int u; h16x2 h; } v; v.u = u; return v.h;
}
#if defined(__has_builtin) && __has_builtin(__builtin_amdgcn_fdot2)
#define DOT2(a, b, c) __builtin_amdgcn_fdot2((a), (b), (c), false)
#else
static __device__ __forceinline__ float dot2_fb(h16x2 a, h16x2 b, float c) {
  return fmaf((float)a[0], (float)b[0], fmaf((float)a[1], (float)b[1], c));
}
#define DOT2(a, b, c) dot2_fb((a), (b), (c))
#endif
static __device__ __forceinline__ float eluf(float z) {
  return z > 0.0f ? z : __expf(z) - 1.0f;
}
static __device__ __forceinline__ float ldin(const void* p, int i, int isf32) {
  return isf32 ? ((const float*)p)[i] : bf2f(((const unsigned short*)p)[i]);
}

// ---------------- K0: dtype detect + canonicalize + CSR + bn fold ----------
__global__ __launch_bounds__(256) void k0_setup(
    const void* __restrict__ adj, const void* __restrict__ imp,
    const void* __restrict__ dww, const void* __restrict__ w1,
    const void* __restrict__ bnF, const void* __restrict__ gw,
    const void* __restrict__ bnsp, const void* __restrict__ sdw,
    const void* __restrict__ pw, const void* __restrict__ bnsep,
    const void* __restrict__ fcw, const void* __restrict__ fcb,
    int* __restrict__ flag, int* __restrict__ deg, int* __restrict__ col,
    float* __restrict__ avals, float* __restrict__ w1c,
    unsigned int* __restrict__ gwh, float* __restrict__ dwn,
    float* __restrict__ sdwc, float* __restrict__ pwc,
    float* __restrict__ fcwc, float* __restrict__ fcbc,
    float* __restrict__ bnFs, float* __restrict__ bnsps,
    float* __restrict__ bnseps)
{
  __shared__ float dwr[1024];
  __shared__ float dsc[16];
  int tid = threadIdx.x;
  int isf32 = (((const float*)adj)[0] == 1.0f) ? 1 : 0;
  if (tid == 0) *flag = isf32;

  for (int i = tid; i < 512;  i += 256) w1c[i]  = ldin(w1, i, isf32);
  // gconv weights packed as f16 pairs: gwh[((l*8+o)*8+i)*4+kp] = (W[2kp],W[2kp+1])
  for (int idx = tid; idx < 768; idx += 256) {
    int kp = idx & 3, i = (idx >> 2) & 7, o = (idx >> 5) & 7, l = idx >> 8;
    int bi = l*512 + (o*8 + i)*8 + 2*kp;
    gwh[idx] = pack2h(ldin(gw, bi, isf32), ldin(gw, bi + 1, isf32));
  }
  for (int i = tid; i < 256;  i += 256) sdwc[i] = ldin(sdw, i, isf32);
  for (int i = tid; i < 256;  i += 256) pwc[i]  = ldin(pw, i, isf32);
  for (int i = tid; i < 8000; i += 256) fcwc[i] = ldin(fcw, i, isf32);
  if (tid < 4) fcbc[tid] = ldin(fcb, tid, isf32);
  for (int i = tid; i < 1024; i += 256) dwr[i] = ldin(dww, i, isf32);

  if (tid < 64) {            // CSR of adjacency (data-driven), self-padded
    int c = tid, n = 0;
    for (int e = 0; e < MAXDEG; ++e) col[c*MAXDEG + e] = c;
    for (int d = 0; d < 64; ++d) {
      if (ldin(adj, c*64 + d, isf32) != 0.0f) {
        if (n < MAXDEG) col[c*MAXDEG + n] = d;
        ++n;
      }
    }
    deg[c] = n < MAXDEG ? n : MAXDEG;
  }
  __syncthreads();
  if (tid < 16) {            // dw norm clamp scale
    float s2 = 0.0f;
    for (int c2 = 0; c2 < 64; ++c2) { float wv = dwr[tid*64 + c2]; s2 += wv*wv; }
    dsc[tid] = fminf(1.0f, 1.0f / fmaxf(sqrtf(s2), 1e-7f));
  }
  if (tid >= 64 && tid < 96) {   // bnF folded scale/shift: 4 stages x 8 ch
    int i = tid - 64, s = i >> 3, f = i & 7;
    float g = ldin(bnF, s*32 + f,      isf32);
    float b = ldin(bnF, s*32 + 8 + f,  isf32);
    float m = ldin(bnF, s*32 + 16 + f, isf32);
    float v = ldin(bnF, s*32 + 24 + f, isf32);
    float sc = g * rsqrtf(v + 1e-3f);
    bnFs[s*16 + f] = sc; bnFs[s*16 + 8 + f] = b - m*sc;
  }
  if (tid >= 96 && tid < 112) {  // bn_sp
    int ch = tid - 96;
    float g = ldin(bnsp, ch, isf32), b = ldin(bnsp, 16 + ch, isf32);
    float m = ldin(bnsp, 32 + ch, isf32), v = ldin(bnsp, 48 + ch, isf32);
    float sc = g * rsqrtf(v + 1e-3f);
    bnsps[ch] = sc; bnsps[16 + ch] = b - m*sc;
  }
  if (tid >= 112 && tid < 128) { // bn_sep
    int ch = tid - 112;
    float g = ldin(bnsep, ch, isf32), b = ldin(bnsep, 16 + ch, isf32);
    float m = ldin(bnsep, 32 + ch, isf32), v = ldin(bnsep, 48 + ch, isf32);
    float sc = g * rsqrtf(v + 1e-3f);
    bnseps[ch] = sc; bnseps[16 + ch] = b - m*sc;
  }
  for (int combo = tid; combo < 3*8*64; combo += 256) {
    int l = combo >> 9, f = (combo >> 6) & 7, c = combo & 63;
    int dg = deg[c];
    for (int e = 0; e < MAXDEG; ++e) {
      float v = 0.0f;
      if (e < dg) {
        int d = col[c*MAXDEG + e];
        v = ldin(adj, c*64 + d, isf32) * ldin(imp, ((l*8 + f)*64 + c)*64 + d, isf32);
      }
      avals[((l*8 + f)*64 + c)*MAXDEG + e] = v;
    }
  }
  __syncthreads();
  for (int i = tid; i < 1024; i += 256) dwn[i] = dwr[i] * dsc[i >> 6];
}

// ---------------- K1: conv1 (64-tap) + bn0. 4 t/thread, SGPR weights -------
// grid (4 t-tiles of 1024, B*C). Stage xs[s] = x[tb-36+s], s in [0,1096):
// base tb-36 makes fp32 float4 (16B) and bf16 uint2 (8B) loads aligned.
// Chunk invariant: A4 = xs[4tid+4+4cc..], B4 = xs[4tid+8+4cc..];
// ev[m] = xs[4tid+5+4cc+m] (= A4.y..B4.w) ~ input t = t0 + (4cc+kk) + j - 31.
__global__ __launch_bounds__(256, 4) void k1_conv1_bn(
    const void* __restrict__ x,               // B,C,T raw dtype
    const float* __restrict__ w1c,            // 8x64 fp32 (uniform -> s_load)
    const float* __restrict__ bnFs,
    const int* __restrict__ flag,
    unsigned short* __restrict__ outp)        // B,F1,C,T f16
{
  __shared__ __align__(16) float xs[1096];
  int tid = threadIdx.x;
  int bc = blockIdx.y;                 // b*64+c
  int b = bc >> 6, c = bc & 63;
  int tb = blockIdx.x * 1024;
  int isf32 = *flag;
  int row = bc * T_;
  if (isf32) {
    const float* xr = (const float*)x + row;
    for (int m = tid; m < 274; m += 256) {
      int tg = tb - 36 + 4*m;
      if (tg >= 0 && tg + 3 < T_) {
        *(float4*)(xs + 4*m) = *(const float4*)(xr + tg);   // 16B aligned
      } else {
        #pragma unroll
        for (int q = 0; q < 4; ++q) {
          int t = tg + q;
          xs[4*m + q] = (t >= 0 && t < T_) ? xr[t] : 0.0f;
        }
      }
    }
  } else {
    const unsigned short* xr = (const unsigned short*)x + row;
    for (int m = tid; m < 274; m += 256) {
      int tg = tb - 36 + 4*m;
      if (tg >= 0 && tg + 3 < T_) {
        uint2 v = *(const uint2*)(xr + tg);                 // 8B aligned
        xs[4*m]     = bf2f((unsigned short)(v.x & 0xFFFFu));
        xs[4*m + 1] = bf2f((unsigned short)(v.x >> 16));
        xs[4*m + 2] = bf2f((unsigned short)(v.y & 0xFFFFu));
        xs[4*m + 3] = bf2f((unsigned short)(v.y >> 16));
      } else {
        #pragma unroll
        for (int q = 0; q < 4; ++q) {
          int t = tg + q;
          xs[4*m + q] = (t >= 0 && t < T_) ? bf2f(xr[t]) : 0.0f;
        }
      }
    }
  }
  __syncthreads();
  int t0 = tb + 4*tid;
  if (t0 >= T_) return;
  float acc[8][4];
  #pragma unroll
  for (int f = 0; f < 8; ++f)
    #pragma unroll
    for (int j = 0; j < 4; ++j) acc[f][j] = 0.0f;
  float4 A4 = *(const float4*)(xs + 4*tid + 4);
  float4 B4 = *(const float4*)(xs + 4*tid + 8);
  for (int cc = 0; cc < 16; ++cc) {
    float ev[7] = {A4.y, A4.z, A4.w, B4.x, B4.y, B4.z, B4.w};
    #pragma unroll
    for (int kk = 0; kk < 4; ++kk) {
      #pragma unroll
      for (int f = 0; f < 8; ++f) {
        float wv = w1c[f*64 + 4*cc + kk];    // uniform -> SGPR
        #pragma unroll
        for (int j = 0; j < 4; ++j) acc[f][j] = fmaf(wv, ev[kk + j], acc[f][j]);
      }
    }
    A4 = B4;
    if (cc < 15) B4 = *(const float4*)(xs + 4*tid + 12 + 4*cc);
  }
  #pragma unroll
  for (int f = 0; f < 8; ++f) {
    float sc = bnFs[f], sh = bnFs[8 + f];
    uint2 st;
    st.x = pack2h(acc[f][0]*sc + sh, acc[f][1]*sc + sh);
    st.y = pack2h(acc[f][2]*sc + sh, acc[f][3]*sc + sh);
    *(uint2*)(outp + ((b*8 + f)*64 + c)*T_ + t0) = st;
  }
}

// ---------------- K2: sparse graph einsum. 8 t/thread, 8 c/block -----------
// grid (2, B*F1*8): by = (bf<<3)|cq, block handles c in [cq*8, cq*8+8).
// 8x wave count vs full-c version; each edge loaded once per block.
__global__ __launch_bounds__(256) void k2_gcn(
    const unsigned short* __restrict__ in,    // B,F1,C,T f16
    unsigned short* __restrict__ outp,        // B,F1,C,T f16
    const int* __restrict__ deg, const int* __restrict__ col,
    const float* __restrict__ avals, int l)
{
  int tid = threadIdx.x;
  int by = blockIdx.y;
  int bf = by >> 3;                    // b*8+f
  int c0 = (by & 7) * 8;
  int tile = blockIdx.x * 256 + tid;
  if (tile >= 500) return;
  int t0 = tile * 8;
  int base = bf * (64 * T_);
  int f = bf & 7;
  const float* av = avals + (l*8 + f) * (64 * MAXDEG);
  for (int c = c0; c < c0 + 8; ++c) {
    int dg = deg[c];                   // uniform -> s_load
    float a[8] = {0,0,0,0,0,0,0,0};
    for (int e = 0; e < dg; ++e) {
      int d = col[c*MAXDEG + e];       // uniform
      float wv = av[c*MAXDEG + e];     // uniform
      uint4 v = *(const uint4*)(in + base + d*T_ + t0);   // 16B aligned
      a[0] = fmaf(wv, lo_h(v.x), a[0]); a[1] = fmaf(wv, hi_h(v.x), a[1]);
      a[2] = fmaf(wv, lo_h(v.y), a[2]); a[3] = fmaf(wv, hi_h(v.y), a[3]);
      a[4] = fmaf(wv, lo_h(v.z), a[4]); a[5] = fmaf(wv, hi_h(v.z), a[5]);
      a[6] = fmaf(wv, lo_h(v.w), a[6]); a[7] = fmaf(wv, hi_h(v.w), a[7]);
    }
    uint4 o;
    o.x = pack2h(a[0], a[1]); o.y = pack2h(a[2], a[3]);
    o.z = pack2h(a[4], a[5]); o.w = pack2h(a[6], a[7]);
    *(uint4*)(outp + base + c*T_ + t0) = o;
  }
}

// ---------------- K3: gconv via dot2 + bn + elu. 8 t/thread (r10 form) -----
// grid (2, B*C). Window u[0..7] = 16 f16 (t0-4..t0+11) via 2 dwordx4;
// od[m] = alignbit odd pairs (7/row, reused across 64 (o,j) pairs).
// Pair for (j,kp): s=j+2kp+1; s odd -> od[(j+2kp)>>1], s even -> u[(j+2kp+1)>>1].
__global__ __launch_bounds__(256) void k3_gconv(
    const unsigned short* __restrict__ in,    // B,F1,C,T f16 (Ah)
    const unsigned int* __restrict__ gwh,     // 3*8*8*4 packed f16 pairs
    const float* __restrict__ bnFs,
    unsigned short* __restrict__ outp,        // B,F1,C,T f16
    int l)
{
  int tid = threadIdx.x;
  int bc = blockIdx.y;                 // b*64+c
  int b = bc >> 6, c = bc & 63;
  int tile = blockIdx.x * 256 + tid;
  if (tile >= 500) return;
  int t0 = tile * 8;
  bool edge = (tile == 0) || (tile == 499);
  float acc[8][8];
  #pragma unroll
  for (int o = 0; o < 8; ++o)
    #pragma unroll
    for (int j = 0; j < 8; ++j) acc[o][j] = 0.0f;
  const unsigned int* gh = gwh + l*256;
  for (int i = 0; i < 8; ++i) {
    int row = ((b*8 + i)*64 + c) * T_;
    unsigned int u[8];
    if (!edge) {
      const unsigned short* rp = in + row + t0 - 4;   // 8B aligned
      uint4 a0 = *(const uint4*)(rp);
      uint4 a1 = *(const uint4*)(rp + 8);
      u[0] = a0.x; u[1] = a0.y; u[2] = a0.z; u[3] = a0.w;
      u[4] = a1.x; u[5] = a1.y; u[6] = a1.z; u[7] = a1.w;
    } else {
      #pragma unroll
      for (int m = 0; m < 8; ++m) {
        int t = t0 - 4 + 2*m;
        unsigned int lo = (t >= 0 && t < T_) ? in[row + t] : 0u;
        unsigned int hi = (t + 1 >= 0 && t + 1 < T_) ? in[row + t + 1] : 0u;
        u[m] = lo | (hi << 16);
      }
    }
    unsigned int od[7];
    #pragma unroll
    for (int m = 0; m < 7; ++m) od[m] = (u[m] >> 16) | (u[m+1] << 16);
    #pragma unroll
    for (int o = 0; o < 8; ++o) {
      #pragma unroll
      for (int kp = 0; kp < 4; ++kp) {
        h16x2 wp = as_h2(gh[(o*8 + i)*4 + kp]);      // uniform -> SGPR
        #pragma unroll
        for (int j = 0; j < 8; ++j) {
          unsigned int pr = (j & 1) ? u[((j + 1) >> 1) + kp]
                                    : od[(j >> 1) + kp];
          acc[o][j] = DOT2(wp, as_h2(pr), acc[o][j]);
        }
      }
    }
  }
  #pragma unroll
  for (int o = 0; o < 8; ++o) {
    float sc = bnFs[(l+1)*16 + o], sh = bnFs[(l+1)*16 + 8 + o];
    uint4 v;
    v.x = pack2h(eluf(acc[o][0]*sc + sh), eluf(acc[o][1]*sc + sh));
    v.y = pack2h(eluf(acc[o][2]*sc + sh), eluf(acc[o][3]*sc + sh));
    v.z = pack2h(eluf(acc[o][4]*sc + sh), eluf(acc[o][5]*sc + sh));
    v.w = pack2h(eluf(acc[o][6]*sc + sh), eluf(acc[o][7]*sc + sh));
    *(uint4*)(outp + ((b*8 + o)*64 + c)*T_ + t0) = v;
  }
}

// ---------------- K4: depthwise-over-C + bn + elu + avgpool4. 8 t/thread ---
__global__ __launch_bounds__(256) void k4_dw(
    const unsigned short* __restrict__ in,    // B,F1,C,T f16
    const float* __restrict__ dwn,            // 16x64 (uniform)
    const float* __restrict__ bnsps,
    float* __restrict__ p1)                   // B,16,1000 fp32
{
  int tid = threadIdx.x;
  int bg = blockIdx.y;                 // b*8+g
  int b = bg >> 3, g = bg & 7;
  int tile = blockIdx.x * 256 + tid;
  if (tile >= 500) return;
  int t0 = tile * 8;
  int base = bg * (64 * T_);
  float a0[8] = {0,0,0,0,0,0,0,0}, a1[8] = {0,0,0,0,0,0,0,0};
  for (int cc = 0; cc < 64; ++cc) {
    float w0 = dwn[(2*g)*64 + cc];     // uniform
    float w1 = dwn[(2*g+1)*64 + cc];   // uniform
    uint4 v = *(const uint4*)(in + base + cc*T_ + t0);
    float h[8];
    h[0] = lo_h(v.x); h[1] = hi_h(v.x); h[2] = lo_h(v.y); h[3] = hi_h(v.y);
    h[4] = lo_h(v.z); h[5] = hi_h(v.z); h[6] = lo_h(v.w); h[7] = hi_h(v.w);
    #pragma unroll
    for (int j = 0; j < 8; ++j) {
      a0[j] = fmaf(w0, h[j], a0[j]);
      a1[j] = fmaf(w1, h[j], a1[j]);
    }
  }
  float sc0 = bnsps[2*g],     sh0 = bnsps[16 + 2*g];
  float sc1 = bnsps[2*g + 1], sh1 = bnsps[16 + 2*g + 1];
  int oi = t0 >> 2;
  float2 r0, r1;
  r0.x = 0.25f * (eluf(a0[0]*sc0+sh0) + eluf(a0[1]*sc0+sh0)
                + eluf(a0[2]*sc0+sh0) + eluf(a0[3]*sc0+sh0));
  r0.y = 0.25f * (eluf(a0[4]*sc0+sh0) + eluf(a0[5]*sc0+sh0)
                + eluf(a0[6]*sc0+sh0) + eluf(a0[7]*sc0+sh0));
  r1.x = 0.25f * (eluf(a1[0]*sc1+sh1) + eluf(a1[1]*sc1+sh1)
                + eluf(a1[2]*sc1+sh1) + eluf(a1[3]*sc1+sh1));
  r1.y = 0.25f * (eluf(a1[4]*sc1+sh1) + eluf(a1[5]*sc1+sh1)
                + eluf(a1[6]*sc1+sh1) + eluf(a1[7]*sc1+sh1));
  *(float2*)(p1 + (b*16 + 2*g)*TP_ + oi)     = r0;
  *(float2*)(p1 + (b*16 + 2*g + 1)*TP_ + oi) = r1;
}

// ---------------- K5: sep depthwise(16) + pointwise(16x16) + bn + elu ------
__global__ __launch_bounds__(256) void k5_sep(
    const float* __restrict__ p1,             // B,16,1000
    const float* __restrict__ sdwc,           // 16x16 (uniform)
    const float* __restrict__ pwc,            // 16x16 (uniform)
    const float* __restrict__ bnseps,
    float* __restrict__ p2)                   // B,16,1001
{
  __shared__ float ps[16*272];
  int tid = threadIdx.x;
  int wq = blockIdx.x, b = blockIdx.y;
  int wb = wq * 256;
  for (int ch = 0; ch < 16; ++ch) {
    for (int s = tid; s < 272; s += 256) {
      int t = wb - 8 + s;
      ps[ch*272 + s] = (t >= 0 && t < TP_) ? p1[(b*16 + ch)*TP_ + t] : 0.0f;
    }
  }
  __syncthreads();
  int w0 = wb + tid;
  if (w0 >= W2_) return;
  float dws[16];
  for (int ch = 0; ch < 16; ++ch) {
    float a = 0.0f;
    #pragma unroll
    for (int k = 0; k < 16; ++k)
      a = fmaf(sdwc[ch*16 + k], ps[ch*272 + tid + k], a);
    dws[ch] = a;
  }
  for (int f = 0; f < 16; ++f) {
    float a = 0.0f;
    #pragma unroll
    for (int ch = 0; ch < 16; ++ch) a = fmaf(pwc[f*16 + ch], dws[ch], a);
    float sc = bnseps[f], sh = bnseps[16 + f];
    p2[(b*16 + f)*W2_ + w0] = eluf(a*sc + sh);
  }
}

// ---------------- K6: avgpool8 (first 1000) + fc ---------------------------
__global__ __launch_bounds__(256) void k6_fc(
    const float* __restrict__ p2,             // B,16,1001
    const float* __restrict__ fcwc,           // 4x2000
    const float* __restrict__ fcbc,           // 4
    const int* __restrict__ flag,
    void* __restrict__ outp)                  // B,4
{
  __shared__ float red[4*256];
  int tid = threadIdx.x;
  int b = blockIdx.x;
  float part[4] = {0.0f, 0.0f, 0.0f, 0.0f};
  for (int idx = tid; idx < 2000; idx += 256) {
    int f = idx / 125, q = idx - f*125;
    const float* src = p2 + (b*16 + f)*W2_ + q*8;
    float s = src[0]+src[1]+src[2]+src[3]+src[4]+src[5]+src[6]+src[7];
    float mval = 0.125f * s;
    #pragma unroll
    for (int n = 0; n < 4; ++n) part[n] = fmaf(fcwc[n*2000 + idx], mval, part[n]);
  }
  #pragma unroll
  for (int n = 0; n < 4; ++n) red[n*256 + tid] = part[n];
  __syncthreads();
  for (int s = 128; s > 0; s >>= 1) {
    if (tid < s) {
      #pragma unroll
      for (int n = 0; n < 4; ++n) red[n*256 + tid] += red[n*256 + tid + s];
    }
    __syncthreads();
  }
  if (tid < 4) {
    float val = red[tid*256] + fcbc[tid];
    if (*flag) ((float*)outp)[b*4 + tid] = val;
    else       ((unsigned short*)outp)[b*4 + tid] = f2bf(val);
  }
}

// ---------------------------------------------------------------------------
extern "C" void kernel_launch(void* const* d_in, const int* in_sizes, int n_in,
                              void* d_out, int out_size, void* d_ws, size_t ws_size,
                              hipStream_t stream) {
  const void* x     = d_in[0];
  const void* adj   = d_in[1];
  const void* w1    = d_in[2];
  const void* bnF   = d_in[3];
  const void* imp   = d_in[4];
  const void* gw    = d_in[5];
  const void* dww   = d_in[6];
  const void* bnsp  = d_in[7];
  const void* sdw   = d_in[8];
  const void* pw    = d_in[9];
  const void* bnsep = d_in[10];
  const void* fcw   = d_in[11];
  const void* fcb   = d_in[12];

  char* w = (char*)d_ws;
  const size_t OFF = 262144000;  // after two 131,072,000-byte f16 buffers
  unsigned short* bufA = (unsigned short*)(w);
  unsigned short* bufB = (unsigned short*)(w + 131072000);
  int*   flag   = (int*)  (w + OFF + 0);
  int*   deg    = (int*)  (w + OFF + 256);
  int*   col    = (int*)  (w + OFF + 512);
  float* avals  = (float*)(w + OFF + 4608);
  float* w1c    = (float*)(w + OFF + 102912);
  unsigned int* gwh = (unsigned int*)(w + OFF + 104960);  // 768 uints
  float* dwn    = (float*)(w + OFF + 108032);
  float* sdwc   = (float*)(w + OFF + 112128);
  float* pwc    = (float*)(w + OFF + 113152);
  float* fcwc   = (float*)(w + OFF + 114176);
  float* fcbc   = (float*)(w + OFF + 146176);
  float* bnFs   = (float*)(w + OFF + 146432);
  float* bnsps  = (float*)(w + OFF + 146688);
  float* bnseps = (float*)(w + OFF + 146944);
  float* p1     = (float*)(w + OFF + 147200);
  float* p2     = (float*)(w + OFF + 2195200);

  k0_setup<<<1, 256, 0, stream>>>(adj, imp, dww, w1, bnF, gw, bnsp, sdw, pw,
                                  bnsep, fcw, fcb, flag, deg, col, avals,
                                  w1c, gwh, dwn, sdwc, pwc, fcwc, fcbc,
                                  bnFs, bnsps, bnseps);
  k1_conv1_bn<<<dim3(4, B_*C_), 256, 0, stream>>>(x, w1c, bnFs, flag, bufA);
  for (int l = 0; l < 3; ++l) {
    k2_gcn<<<dim3(2, B_*F1_*8), 256, 0, stream>>>(bufA, bufB, deg, col, avals, l);
    k3_gconv<<<dim3(4, B_*C_), 256, 0, stream>>>(bufB, gwh, bnFs, bufA, l);
  }
  k4_dw<<<dim3(2, B_*F1_), 256, 0, stream>>>(bufA, dwn, bnsps, p1);
  k5_sep<<<dim3(4, B_), 256, 0, stream>>>(p1, sdwc, pwc, bnseps, p2);
  k6_fc<<<32, 256, 0, stream>>>(p2, fcwc, fcbc, flag, d_out);
}

// Round 13
// 806.759 us; speedup vs baseline: 1.2801x; 1.2801x over previous
//
#include <hip/hip_runtime.h>

// GCN-EEGNet forward, MI355X. Dtype-adaptive (fp32/bf16 detected in K0 via
// adjacency sentinel). Weights in ws, wave-uniform -> SGPR. Intermediates
// f16. Round-13: r12's ONLY bug fixed — k3 was launched grid.x=4 with a
// 256-tile/block body, creating 4096 empty blocks resonant with the XCD
// round-robin (ids 2,3 mod 4 -> XCDs 2,3,6,7 all-empty -> half the chip
// idle; Occ & VALUBusy exactly halved). k3 grid back to (2, B*C).
// LESSON: never launch empty blocks in a pattern resonant with id%8 XCD rr.
// Pipeline: K0 -> K1 conv1+bn -> 3x [K2 graph einsum -> K3 gconv+bn+elu] ->
// K4 dw+bn+elu+pool4 -> K5 sep+bn+elu -> K6 pool8+fc.

#define B_   32
#define C_   64
#define T_   4000
#define F1_  8
#define TP_  1000
#define W2_  1001
#define MAXDEG 16

typedef _Float16 h16x2 __attribute__((ext_vector_type(2)));

static __device__ __forceinline__ float bf2f(unsigned short h) {
  union { unsigned int u; float f; } v; v.u = ((unsigned int)h) << 16; return v.f;
}
static __device__ __forceinline__ unsigned short f2bf(float f) {
  union { float f; unsigned int u; } v; v.f = f;
  unsigned int r = v.u + 0x7FFFu + ((v.u >> 16) & 1u);
  return (unsigned short)(r >> 16);
}
static __device__ __forceinline__ float lo_h(unsigned int u) {
  union { unsigned int u; _Float16 h[2]; } v; v.u = u; return (float)v.h[0];
}
static __device__ __forceinline__ float hi_h(unsigned int u) {
  union { unsigned int u; _Float16 h[2]; } v; v.u = u; return (float)v.h[1];
}
static __device__ __forceinline__ unsigned int pack2h(float a, float b) {
  union { _Float16 h[2]; unsigned int u; } v;
  v.h[0] = (_Float16)a; v.h[1] = (_Float16)b; return v.u;
}
static __device__ __forceinline__ h16x2 as_h2(unsigned int u) {
  union { unsigned int u; h16x2 h; } v; v.u = u; return v.h;
}
#if defined(__has_builtin) && __has_builtin(__builtin_amdgcn_fdot2)
#define DOT2(a, b, c) __builtin_amdgcn_fdot2((a), (b), (c), false)
#else
static __device__ __forceinline__ float dot2_fb(h16x2 a, h16x2 b, float c) {
  return fmaf((float)a[0], (float)b[0], fmaf((float)a[1], (float)b[1], c));
}
#define DOT2(a, b, c) dot2_fb((a), (b), (c))
#endif
static __device__ __forceinline__ float eluf(float z) {
  return z > 0.0f ? z : __expf(z) - 1.0f;
}
static __device__ __forceinline__ float ldin(const void* p, int i, int isf32) {
  return isf32 ? ((const float*)p)[i] : bf2f(((const unsigned short*)p)[i]);
}

// ---------------- K0: dtype detect + canonicalize + CSR + bn fold ----------
__global__ __launch_bounds__(256) void k0_setup(
    const void* __restrict__ adj, const void* __restrict__ imp,
    const void* __restrict__ dww, const void* __restrict__ w1,
    const void* __restrict__ bnF, const void* __restrict__ gw,
    const void* __restrict__ bnsp, const void* __restrict__ sdw,
    const void* __restrict__ pw, const void* __restrict__ bnsep,
    const void* __restrict__ fcw, const void* __restrict__ fcb,
    int* __restrict__ flag, int* __restrict__ deg, int* __restrict__ col,
    float* __restrict__ avals, float* __restrict__ w1c,
    unsigned int* __restrict__ gwh, float* __restrict__ dwn,
    float* __restrict__ sdwc, float* __restrict__ pwc,
    float* __restrict__ fcwc, float* __restrict__ fcbc,
    float* __restrict__ bnFs, float* __restrict__ bnsps,
    float* __restrict__ bnseps)
{
  __shared__ float dwr[1024];
  __shared__ float dsc[16];
  int tid = threadIdx.x;
  int isf32 = (((const float*)adj)[0] == 1.0f) ? 1 : 0;
  if (tid == 0) *flag = isf32;

  for (int i = tid; i < 512;  i += 256) w1c[i]  = ldin(w1, i, isf32);
  // gconv weights packed as f16 pairs: gwh[((l*8+o)*8+i)*4+kp] = (W[2kp],W[2kp+1])
  for (int idx = tid; idx < 768; idx += 256) {
    int kp = idx & 3, i = (idx >> 2) & 7, o = (idx >> 5) & 7, l = idx >> 8;
    int bi = l*512 + (o*8 + i)*8 + 2*kp;
    gwh[idx] = pack2h(ldin(gw, bi, isf32), ldin(gw, bi + 1, isf32));
  }
  for (int i = tid; i < 256;  i += 256) sdwc[i] = ldin(sdw, i, isf32);
  for (int i = tid; i < 256;  i += 256) pwc[i]  = ldin(pw, i, isf32);
  for (int i = tid; i < 8000; i += 256) fcwc[i] = ldin(fcw, i, isf32);
  if (tid < 4) fcbc[tid] = ldin(fcb, tid, isf32);
  for (int i = tid; i < 1024; i += 256) dwr[i] = ldin(dww, i, isf32);

  if (tid < 64) {            // CSR of adjacency (data-driven), self-padded
    int c = tid, n = 0;
    for (int e = 0; e < MAXDEG; ++e) col[c*MAXDEG + e] = c;
    for (int d = 0; d < 64; ++d) {
      if (ldin(adj, c*64 + d, isf32) != 0.0f) {
        if (n < MAXDEG) col[c*MAXDEG + n] = d;
        ++n;
      }
    }
    deg[c] = n < MAXDEG ? n : MAXDEG;
  }
  __syncthreads();
  if (tid < 16) {            // dw norm clamp scale
    float s2 = 0.0f;
    for (int c2 = 0; c2 < 64; ++c2) { float wv = dwr[tid*64 + c2]; s2 += wv*wv; }
    dsc[tid] = fminf(1.0f, 1.0f / fmaxf(sqrtf(s2), 1e-7f));
  }
  if (tid >= 64 && tid < 96) {   // bnF folded scale/shift: 4 stages x 8 ch
    int i = tid - 64, s = i >> 3, f = i & 7;
    float g = ldin(bnF, s*32 + f,      isf32);
    float b = ldin(bnF, s*32 + 8 + f,  isf32);
    float m = ldin(bnF, s*32 + 16 + f, isf32);
    float v = ldin(bnF, s*32 + 24 + f, isf32);
    float sc = g * rsqrtf(v + 1e-3f);
    bnFs[s*16 + f] = sc; bnFs[s*16 + 8 + f] = b - m*sc;
  }
  if (tid >= 96 && tid < 112) {  // bn_sp
    int ch = tid - 96;
    float g = ldin(bnsp, ch, isf32), b = ldin(bnsp, 16 + ch, isf32);
    float m = ldin(bnsp, 32 + ch, isf32), v = ldin(bnsp, 48 + ch, isf32);
    float sc = g * rsqrtf(v + 1e-3f);
    bnsps[ch] = sc; bnsps[16 + ch] = b - m*sc;
  }
  if (tid >= 112 && tid < 128) { // bn_sep
    int ch = tid - 112;
    float g = ldin(bnsep, ch, isf32), b = ldin(bnsep, 16 + ch, isf32);
    float m = ldin(bnsep, 32 + ch, isf32), v = ldin(bnsep, 48 + ch, isf32);
    float sc = g * rsqrtf(v + 1e-3f);
    bnseps[ch] = sc; bnseps[16 + ch] = b - m*sc;
  }
  for (int combo = tid; combo < 3*8*64; combo += 256) {
    int l = combo >> 9, f = (combo >> 6) & 7, c = combo & 63;
    int dg = deg[c];
    for (int e = 0; e < MAXDEG; ++e) {
      float v = 0.0f;
      if (e < dg) {
        int d = col[c*MAXDEG + e];
        v = ldin(adj, c*64 + d, isf32) * ldin(imp, ((l*8 + f)*64 + c)*64 + d, isf32);
      }
      avals[((l*8 + f)*64 + c)*MAXDEG + e] = v;
    }
  }
  __syncthreads();
  for (int i = tid; i < 1024; i += 256) dwn[i] = dwr[i] * dsc[i >> 6];
}

// ---------------- K1: conv1 (64-tap) + bn0. 4 t/thread, SGPR weights -------
// grid (4 t-tiles of 1024, B*C). Stage xs[s] = x[tb-36+s], s in [0,1096):
// base tb-36 makes fp32 float4 (16B) and bf16 uint2 (8B) loads aligned.
// Chunk invariant: A4 = xs[4tid+4+4cc..], B4 = xs[4tid+8+4cc..];
// ev[m] = xs[4tid+5+4cc+m] (= A4.y..B4.w) ~ input t = t0 + (4cc+kk) + j - 31.
__global__ __launch_bounds__(256, 4) void k1_conv1_bn(
    const void* __restrict__ x,               // B,C,T raw dtype
    const float* __restrict__ w1c,            // 8x64 fp32 (uniform -> s_load)
    const float* __restrict__ bnFs,
    const int* __restrict__ flag,
    unsigned short* __restrict__ outp)        // B,F1,C,T f16
{
  __shared__ __align__(16) float xs[1096];
  int tid = threadIdx.x;
  int bc = blockIdx.y;                 // b*64+c
  int b = bc >> 6, c = bc & 63;
  int tb = blockIdx.x * 1024;
  int isf32 = *flag;
  int row = bc * T_;
  if (isf32) {
    const float* xr = (const float*)x + row;
    for (int m = tid; m < 274; m += 256) {
      int tg = tb - 36 + 4*m;
      if (tg >= 0 && tg + 3 < T_) {
        *(float4*)(xs + 4*m) = *(const float4*)(xr + tg);   // 16B aligned
      } else {
        #pragma unroll
        for (int q = 0; q < 4; ++q) {
          int t = tg + q;
          xs[4*m + q] = (t >= 0 && t < T_) ? xr[t] : 0.0f;
        }
      }
    }
  } else {
    const unsigned short* xr = (const unsigned short*)x + row;
    for (int m = tid; m < 274; m += 256) {
      int tg = tb - 36 + 4*m;
      if (tg >= 0 && tg + 3 < T_) {
        uint2 v = *(const uint2*)(xr + tg);                 // 8B aligned
        xs[4*m]     = bf2f((unsigned short)(v.x & 0xFFFFu));
        xs[4*m + 1] = bf2f((unsigned short)(v.x >> 16));
        xs[4*m + 2] = bf2f((unsigned short)(v.y & 0xFFFFu));
        xs[4*m + 3] = bf2f((unsigned short)(v.y >> 16));
      } else {
        #pragma unroll
        for (int q = 0; q < 4; ++q) {
          int t = tg + q;
          xs[4*m + q] = (t >= 0 && t < T_) ? bf2f(xr[t]) : 0.0f;
        }
      }
    }
  }
  __syncthreads();
  int t0 = tb + 4*tid;
  if (t0 >= T_) return;
  float acc[8][4];
  #pragma unroll
  for (int f = 0; f < 8; ++f)
    #pragma unroll
    for (int j = 0; j < 4; ++j) acc[f][j] = 0.0f;
  float4 A4 = *(const float4*)(xs + 4*tid + 4);
  float4 B4 = *(const float4*)(xs + 4*tid + 8);
  for (int cc = 0; cc < 16; ++cc) {
    float ev[7] = {A4.y, A4.z, A4.w, B4.x, B4.y, B4.z, B4.w};
    #pragma unroll
    for (int kk = 0; kk < 4; ++kk) {
      #pragma unroll
      for (int f = 0; f < 8; ++f) {
        float wv = w1c[f*64 + 4*cc + kk];    // uniform -> SGPR
        #pragma unroll
        for (int j = 0; j < 4; ++j) acc[f][j] = fmaf(wv, ev[kk + j], acc[f][j]);
      }
    }
    A4 = B4;
    if (cc < 15) B4 = *(const float4*)(xs + 4*tid + 12 + 4*cc);
  }
  #pragma unroll
  for (int f = 0; f < 8; ++f) {
    float sc = bnFs[f], sh = bnFs[8 + f];
    uint2 st;
    st.x = pack2h(acc[f][0]*sc + sh, acc[f][1]*sc + sh);
    st.y = pack2h(acc[f][2]*sc + sh, acc[f][3]*sc + sh);
    *(uint2*)(outp + ((b*8 + f)*64 + c)*T_ + t0) = st;
  }
}

// ---------------- K2: sparse graph einsum. 8 t/thread, 8 c/block -----------
// grid (2, B*F1*8): by = (bf<<3)|cq, block handles c in [cq*8, cq*8+8).
// 8x wave count vs full-c version; each edge loaded once per block.
__global__ __launch_bounds__(256) void k2_gcn(
    const unsigned short* __restrict__ in,    // B,F1,C,T f16
    unsigned short* __restrict__ outp,        // B,F1,C,T f16
    const int* __restrict__ deg, const int* __restrict__ col,
    const float* __restrict__ avals, int l)
{
  int tid = threadIdx.x;
  int by = blockIdx.y;
  int bf = by >> 3;                    // b*8+f
  int c0 = (by & 7) * 8;
  int tile = blockIdx.x * 256 + tid;
  if (tile >= 500) return;
  int t0 = tile * 8;
  int base = bf * (64 * T_);
  int f = bf & 7;
  const float* av = avals + (l*8 + f) * (64 * MAXDEG);
  for (int c = c0; c < c0 + 8; ++c) {
    int dg = deg[c];                   // uniform -> s_load
    float a[8] = {0,0,0,0,0,0,0,0};
    for (int e = 0; e < dg; ++e) {
      int d = col[c*MAXDEG + e];       // uniform
      float wv = av[c*MAXDEG + e];     // uniform
      uint4 v = *(const uint4*)(in + base + d*T_ + t0);   // 16B aligned
      a[0] = fmaf(wv, lo_h(v.x), a[0]); a[1] = fmaf(wv, hi_h(v.x), a[1]);
      a[2] = fmaf(wv, lo_h(v.y), a[2]); a[3] = fmaf(wv, hi_h(v.y), a[3]);
      a[4] = fmaf(wv, lo_h(v.z), a[4]); a[5] = fmaf(wv, hi_h(v.z), a[5]);
      a[6] = fmaf(wv, lo_h(v.w), a[6]); a[7] = fmaf(wv, hi_h(v.w), a[7]);
    }
    uint4 o;
    o.x = pack2h(a[0], a[1]); o.y = pack2h(a[2], a[3]);
    o.z = pack2h(a[4], a[5]); o.w = pack2h(a[6], a[7]);
    *(uint4*)(outp + base + c*T_ + t0) = o;
  }
}

// ---------------- K3: gconv via dot2 + bn + elu. 8 t/thread (r10 form) -----
// grid (2, B*C) — MUST be 2 (500 tiles / 256 per block); empty blocks from
// a larger grid resonate with XCD round-robin and idle half the chip (r12).
// Window u[0..7] = 16 f16 via 2 dwordx4; od[m] = alignbit odd pairs.
__global__ __launch_bounds__(256) void k3_gconv(
    const unsigned short* __restrict__ in,    // B,F1,C,T f16 (Ah)
    const unsigned int* __restrict__ gwh,     // 3*8*8*4 packed f16 pairs
    const float* __restrict__ bnFs,
    unsigned short* __restrict__ outp,        // B,F1,C,T f16
    int l)
{
  int tid = threadIdx.x;
  int bc = blockIdx.y;                 // b*64+c
  int b = bc >> 6, c = bc & 63;
  int tile = blockIdx.x * 256 + tid;
  if (tile >= 500) return;
  int t0 = tile * 8;
  bool edge = (tile == 0) || (tile == 499);
  float acc[8][8];
  #pragma unroll
  for (int o = 0; o < 8; ++o)
    #pragma unroll
    for (int j = 0; j < 8; ++j) acc[o][j] = 0.0f;
  const unsigned int* gh = gwh + l*256;
  for (int i = 0; i < 8; ++i) {
    int row = ((b*8 + i)*64 + c) * T_;
    unsigned int u[8];
    if (!edge) {
      const unsigned short* rp = in + row + t0 - 4;   // 8B aligned
      uint4 a0 = *(const uint4*)(rp);
      uint4 a1 = *(const uint4*)(rp + 8);
      u[0] = a0.x; u[1] = a0.y; u[2] = a0.z; u[3] = a0.w;
      u[4] = a1.x; u[5] = a1.y; u[6] = a1.z; u[7] = a1.w;
    } else {
      #pragma unroll
      for (int m = 0; m < 8; ++m) {
        int t = t0 - 4 + 2*m;
        unsigned int lo = (t >= 0 && t < T_) ? in[row + t] : 0u;
        unsigned int hi = (t + 1 >= 0 && t + 1 < T_) ? in[row + t + 1] : 0u;
        u[m] = lo | (hi << 16);
      }
    }
    unsigned int od[7];
    #pragma unroll
    for (int m = 0; m < 7; ++m) od[m] = (u[m] >> 16) | (u[m+1] << 16);
    #pragma unroll
    for (int o = 0; o < 8; ++o) {
      #pragma unroll
      for (int kp = 0; kp < 4; ++kp) {
        h16x2 wp = as_h2(gh[(o*8 + i)*4 + kp]);      // uniform -> SGPR
        #pragma unroll
        for (int j = 0; j < 8; ++j) {
          unsigned int pr = (j & 1) ? u[((j + 1) >> 1) + kp]
                                    : od[(j >> 1) + kp];
          acc[o][j] = DOT2(wp, as_h2(pr), acc[o][j]);
        }
      }
    }
  }
  #pragma unroll
  for (int o = 0; o < 8; ++o) {
    float sc = bnFs[(l+1)*16 + o], sh = bnFs[(l+1)*16 + 8 + o];
    uint4 v;
    v.x = pack2h(eluf(acc[o][0]*sc + sh), eluf(acc[o][1]*sc + sh));
    v.y = pack2h(eluf(acc[o][2]*sc + sh), eluf(acc[o][3]*sc + sh));
    v.z = pack2h(eluf(acc[o][4]*sc + sh), eluf(acc[o][5]*sc + sh));
    v.w = pack2h(eluf(acc[o][6]*sc + sh), eluf(acc[o][7]*sc + sh));
    *(uint4*)(outp + ((b*8 + o)*64 + c)*T_ + t0) = v;
  }
}

// ---------------- K4: depthwise-over-C + bn + elu + avgpool4. 8 t/thread ---
__global__ __launch_bounds__(256) void k4_dw(
    const unsigned short* __restrict__ in,    // B,F1,C,T f16
    const float* __restrict__ dwn,            // 16x64 (uniform)
    const float* __restrict__ bnsps,
    float* __restrict__ p1)                   // B,16,1000 fp32
{
  int tid = threadIdx.x;
  int bg = blockIdx.y;                 // b*8+g
  int b = bg >> 3, g = bg & 7;
  int tile = blockIdx.x * 256 + tid;
  if (tile >= 500) return;
  int t0 = tile * 8;
  int base = bg * (64 * T_);
  float a0[8] = {0,0,0,0,0,0,0,0}, a1[8] = {0,0,0,0,0,0,0,0};
  for (int cc = 0; cc < 64; ++cc) {
    float w0 = dwn[(2*g)*64 + cc];     // uniform
    float w1 = dwn[(2*g+1)*64 + cc];   // uniform
    uint4 v = *(const uint4*)(in + base + cc*T_ + t0);
    float h[8];
    h[0] = lo_h(v.x); h[1] = hi_h(v.x); h[2] = lo_h(v.y); h[3] = hi_h(v.y);
    h[4] = lo_h(v.z); h[5] = hi_h(v.z); h[6] = lo_h(v.w); h[7] = hi_h(v.w);
    #pragma unroll
    for (int j = 0; j < 8; ++j) {
      a0[j] = fmaf(w0, h[j], a0[j]);
      a1[j] = fmaf(w1, h[j], a1[j]);
    }
  }
  float sc0 = bnsps[2*g],     sh0 = bnsps[16 + 2*g];
  float sc1 = bnsps[2*g + 1], sh1 = bnsps[16 + 2*g + 1];
  int oi = t0 >> 2;
  float2 r0, r1;
  r0.x = 0.25f * (eluf(a0[0]*sc0+sh0) + eluf(a0[1]*sc0+sh0)
                + eluf(a0[2]*sc0+sh0) + eluf(a0[3]*sc0+sh0));
  r0.y = 0.25f * (eluf(a0[4]*sc0+sh0) + eluf(a0[5]*sc0+sh0)
                + eluf(a0[6]*sc0+sh0) + eluf(a0[7]*sc0+sh0));
  r1.x = 0.25f * (eluf(a1[0]*sc1+sh1) + eluf(a1[1]*sc1+sh1)
                + eluf(a1[2]*sc1+sh1) + eluf(a1[3]*sc1+sh1));
  r1.y = 0.25f * (eluf(a1[4]*sc1+sh1) + eluf(a1[5]*sc1+sh1)
                + eluf(a1[6]*sc1+sh1) + eluf(a1[7]*sc1+sh1));
  *(float2*)(p1 + (b*16 + 2*g)*TP_ + oi)     = r0;
  *(float2*)(p1 + (b*16 + 2*g + 1)*TP_ + oi) = r1;
}

// ---------------- K5: sep depthwise(16) + pointwise(16x16) + bn + elu ------
__global__ __launch_bounds__(256) void k5_sep(
    const float* __restrict__ p1,             // B,16,1000
    const float* __restrict__ sdwc,           // 16x16 (uniform)
    const float* __restrict__ pwc,            // 16x16 (uniform)
    const float* __restrict__ bnseps,
    float* __restrict__ p2)                   // B,16,1001
{
  __shared__ float ps[16*272];
  int tid = threadIdx.x;
  int wq = blockIdx.x, b = blockIdx.y;
  int wb = wq * 256;
  for (int ch = 0; ch < 16; ++ch) {
    for (int s = tid; s < 272; s += 256) {
      int t = wb - 8 + s;
      ps[ch*272 + s] = (t >= 0 && t < TP_) ? p1[(b*16 + ch)*TP_ + t] : 0.0f;
    }
  }
  __syncthreads();
  int w0 = wb + tid;
  if (w0 >= W2_) return;
  float dws[16];
  for (int ch = 0; ch < 16; ++ch) {
    float a = 0.0f;
    #pragma unroll
    for (int k = 0; k < 16; ++k)
      a = fmaf(sdwc[ch*16 + k], ps[ch*272 + tid + k], a);
    dws[ch] = a;
  }
  for (int f = 0; f < 16; ++f) {
    float a = 0.0f;
    #pragma unroll
    for (int ch = 0; ch < 16; ++ch) a = fmaf(pwc[f*16 + ch], dws[ch], a);
    float sc = bnseps[f], sh = bnseps[16 + f];
    p2[(b*16 + f)*W2_ + w0] = eluf(a*sc + sh);
  }
}

// ---------------- K6: avgpool8 (first 1000) + fc ---------------------------
__global__ __launch_bounds__(256) void k6_fc(
    const float* __restrict__ p2,             // B,16,1001
    const float* __restrict__ fcwc,           // 4x2000
    const float* __restrict__ fcbc,           // 4
    const int* __restrict__ flag,
    void* __restrict__ outp)                  // B,4
{
  __shared__ float red[4*256];
  int tid = threadIdx.x;
  int b = blockIdx.x;
  float part[4] = {0.0f, 0.0f, 0.0f, 0.0f};
  for (int idx = tid; idx < 2000; idx += 256) {
    int f = idx / 125, q = idx - f*125;
    const float* src = p2 + (b*16 + f)*W2_ + q*8;
    float s = src[0]+src[1]+src[2]+src[3]+src[4]+src[5]+src[6]+src[7];
    float mval = 0.125f * s;
    #pragma unroll
    for (int n = 0; n < 4; ++n) part[n] = fmaf(fcwc[n*2000 + idx], mval, part[n]);
  }
  #pragma unroll
  for (int n = 0; n < 4; ++n) red[n*256 + tid] = part[n];
  __syncthreads();
  for (int s = 128; s > 0; s >>= 1) {
    if (tid < s) {
      #pragma unroll
      for (int n = 0; n < 4; ++n) red[n*256 + tid] += red[n*256 + tid + s];
    }
    __syncthreads();
  }
  if (tid < 4) {
    float val = red[tid*256] + fcbc[tid];
    if (*flag) ((float*)outp)[b*4 + tid] = val;
    else       ((unsigned short*)outp)[b*4 + tid] = f2bf(val);
  }
}

// ---------------------------------------------------------------------------
extern "C" void kernel_launch(void* const* d_in, const int* in_sizes, int n_in,
                              void* d_out, int out_size, void* d_ws, size_t ws_size,
                              hipStream_t stream) {
  const void* x     = d_in[0];
  const void* adj   = d_in[1];
  const void* w1    = d_in[2];
  const void* bnF   = d_in[3];
  const void* imp   = d_in[4];
  const void* gw    = d_in[5];
  const void* dww   = d_in[6];
  const void* bnsp  = d_in[7];
  const void* sdw   = d_in[8];
  const void* pw    = d_in[9];
  const void* bnsep = d_in[10];
  const void* fcw   = d_in[11];
  const void* fcb   = d_in[12];

  char* w = (char*)d_ws;
  const size_t OFF = 262144000;  // after two 131,072,000-byte f16 buffers
  unsigned short* bufA = (unsigned short*)(w);
  unsigned short* bufB = (unsigned short*)(w + 131072000);
  int*   flag   = (int*)  (w + OFF + 0);
  int*   deg    = (int*)  (w + OFF + 256);
  int*   col    = (int*)  (w + OFF + 512);
  float* avals  = (float*)(w + OFF + 4608);
  float* w1c    = (float*)(w + OFF + 102912);
  unsigned int* gwh = (unsigned int*)(w + OFF + 104960);  // 768 uints
  float* dwn    = (float*)(w + OFF + 108032);
  float* sdwc   = (float*)(w + OFF + 112128);
  float* pwc    = (float*)(w + OFF + 113152);
  float* fcwc   = (float*)(w + OFF + 114176);
  float* fcbc   = (float*)(w + OFF + 146176);
  float* bnFs   = (float*)(w + OFF + 146432);
  float* bnsps  = (float*)(w + OFF + 146688);
  float* bnseps = (float*)(w + OFF + 146944);
  float* p1     = (float*)(w + OFF + 147200);
  float* p2     = (float*)(w + OFF + 2195200);

  k0_setup<<<1, 256, 0, stream>>>(adj, imp, dww, w1, bnF, gw, bnsp, sdw, pw,
                                  bnsep, fcw, fcb, flag, deg, col, avals,
                                  w1c, gwh, dwn, sdwc, pwc, fcwc, fcbc,
                                  bnFs, bnsps, bnseps);
  k1_conv1_bn<<<dim3(4, B_*C_), 256, 0, stream>>>(x, w1c, bnFs, flag, bufA);
  for (int l = 0; l < 3; ++l) {
    k2_gcn<<<dim3(2, B_*F1_*8), 256, 0, stream>>>(bufA, bufB, deg, col, avals, l);
    k3_gconv<<<dim3(2, B_*C_), 256, 0, stream>>>(bufB, gwh, bnFs, bufA, l);
  }
  k4_dw<<<dim3(2, B_*F1_), 256, 0, stream>>>(bufA, dwn, bnsps, p1);
  k5_sep<<<dim3(4, B_), 256, 0, stream>>>(p1, sdwc, pwc, bnseps, p2);
  k6_fc<<<32, 256, 0, stream>>>(p2, fcwc, fcbc, flag, d_out);
}